// Round 5
// baseline (7723.516 us; speedup 1.0000x reference)
//
#include <hip/hip_runtime.h>
#include <math.h>

// ---------------------------------------------------------------------------
// TDS decoder R9 (= R8 hardened): 128 persistent blocks x 1024 threads,
// tagged single-writer protocol with sticky-mask sweeps.
//  - Producer: after barrier C, wave0 pushes its 41 fold-partials as {f32,tag}
//    8B atomics in ONE store instruction. No ack wait, no release counter,
//    no zero pass: visibility rides the tag (atomic 8B unit).
//  - Consumer: sweep = detection+gather fused. Sticky `seen` mask, `want`
//    snapshot per retry so loads stay pipelined and retries only touch
//    unseen sources. Split: wave0 srcs 0-63, wave2 srcs 64-127, wave1 hp;
//    combine via LDS flags.
//  - gh rows self-tagged (2-buf): GRU waves poll their 3 entries directly,
//    published during the PREVIOUS iteration's dots -> full overlap.
//  - K rows in REGISTERS (R6-validated config; R8's 128KB static LDS was the
//    only untested resource demand and is the suspected container-killer).
//  - 2-deep buffers everywhere; 2-epoch induction makes overwrite safe.
// ---------------------------------------------------------------------------

#define NV      40
#define TENC    8192
#define MAXLEN  200
#define EOS_IDX 38
#define NB      128
#define NT      1024
#define NW      16
#define ROWS    64                    /* enc rows per block                 */
#define RPW     4                     /* enc rows per wave                  */
#define NAUX    12                    /* gh rows per block (1536/128)       */
#define RSTRIDE 82                    /* floats per record (41 cols x 8B)   */
#define HSTRIDE 84                    /* hp buffer stride (floats)          */
#define SCALE   0.04419417382415922f  /* 1/sqrt(512) */

/* ws layout (floats, all 8B-aligned) */
#define WS_RDY  0                             /* 128 x 8B = 256             */
#define WS_REC  256                           /* 2 x 128 x 82 = 20992       */
#define WS_HP   (WS_REC + 2 * NB * RSTRIDE)   /* 21248: 2 x 84              */
#define WS_GHT  (WS_HP + 2 * HSTRIDE)         /* 21416: 2 x 1536 x 2 = 6144 */
#define WS_GI   (WS_GHT + 2 * 3072)           /* 27560: 40 x 1536           */
/* total = 27560 + 61440 = 89000 floats (356 KB) <= R6-proven 358 KB */

typedef unsigned long long u64;

__device__ __forceinline__ void st_tag(float* p, float v, int tag) {
  const u64 x = ((u64)(unsigned)tag << 32) | (u64)__float_as_uint(v);
  __hip_atomic_store((u64*)p, x, __ATOMIC_RELAXED, __HIP_MEMORY_SCOPE_AGENT);
}
__device__ __forceinline__ void st_tag_rel(float* p, float v, int tag) {
  const u64 x = ((u64)(unsigned)tag << 32) | (u64)__float_as_uint(v);
  __hip_atomic_store((u64*)p, x, __ATOMIC_RELEASE, __HIP_MEMORY_SCOPE_AGENT);
}
__device__ __forceinline__ u64 ld_tag(float* p) {
  return __hip_atomic_load((u64*)p, __ATOMIC_RELAXED, __HIP_MEMORY_SCOPE_AGENT);
}
#define TAGOF(x) ((int)(unsigned)((x) >> 32))
#define VALOF(x) __uint_as_float((unsigned)(x))

__device__ __forceinline__ int ld_lds_acq(int* p) {
  return __hip_atomic_load(p, __ATOMIC_ACQUIRE, __HIP_MEMORY_SCOPE_WORKGROUP);
}
__device__ __forceinline__ void st_lds_rel(int* p, int v) {
  __hip_atomic_store(p, v, __ATOMIC_RELEASE, __HIP_MEMORY_SCOPE_WORKGROUP);
}

__device__ __forceinline__ float wred(float s) {
#pragma unroll
  for (int o = 32; o > 0; o >>= 1) s += __shfl_xor(s, o, 64);
  return s;
}
__device__ __forceinline__ float dot8(float4 a0, float4 a1, float4 b0,
                                      float4 b1) {
  return a0.x * b0.x + a0.y * b0.y + a0.z * b0.z + a0.w * b0.w +
         a1.x * b1.x + a1.y * b1.y + a1.z * b1.z + a1.w * b1.w;
}
__device__ __forceinline__ float wdot512(const float* __restrict__ a,
                                         const float* __restrict__ b) {
  const int l = threadIdx.x & 63;
  const float4 a0 = ((const float4*)a)[l];
  const float4 a1 = ((const float4*)a)[l + 64];
  const float4 b0 = ((const float4*)b)[l];
  const float4 b1 = ((const float4*)b)[l + 64];
  return wred(dot8(a0, a1, b0, b1));
}

// Sticky-mask pipelined sweep over 64 sources for this lane's column.
// Loads grouped 8-wide (want snapshot -> no loop-carried dep on loads).
__device__ __forceinline__ float sweep64(float* rb, int t, int lane) {
  float acc = 0.0f;
  u64 seen = 0;
  const bool act = (lane < 41);
  for (;;) {
    const u64 want = ~seen;
    if (act) {
#pragma unroll
      for (int g = 0; g < 8; ++g) {
        const int s0 = g * 8;
        u64 a0 = 0, a1 = 0, a2 = 0, a3 = 0, a4 = 0, a5 = 0, a6 = 0, a7 = 0;
        if ((want >> (s0 + 0)) & 1) a0 = ld_tag(&rb[(s0 + 0) * RSTRIDE + 2 * lane]);
        if ((want >> (s0 + 1)) & 1) a1 = ld_tag(&rb[(s0 + 1) * RSTRIDE + 2 * lane]);
        if ((want >> (s0 + 2)) & 1) a2 = ld_tag(&rb[(s0 + 2) * RSTRIDE + 2 * lane]);
        if ((want >> (s0 + 3)) & 1) a3 = ld_tag(&rb[(s0 + 3) * RSTRIDE + 2 * lane]);
        if ((want >> (s0 + 4)) & 1) a4 = ld_tag(&rb[(s0 + 4) * RSTRIDE + 2 * lane]);
        if ((want >> (s0 + 5)) & 1) a5 = ld_tag(&rb[(s0 + 5) * RSTRIDE + 2 * lane]);
        if ((want >> (s0 + 6)) & 1) a6 = ld_tag(&rb[(s0 + 6) * RSTRIDE + 2 * lane]);
        if ((want >> (s0 + 7)) & 1) a7 = ld_tag(&rb[(s0 + 7) * RSTRIDE + 2 * lane]);
        if (TAGOF(a0) == t) { acc += VALOF(a0); seen |= 1ull << (s0 + 0); }
        if (TAGOF(a1) == t) { acc += VALOF(a1); seen |= 1ull << (s0 + 1); }
        if (TAGOF(a2) == t) { acc += VALOF(a2); seen |= 1ull << (s0 + 2); }
        if (TAGOF(a3) == t) { acc += VALOF(a3); seen |= 1ull << (s0 + 3); }
        if (TAGOF(a4) == t) { acc += VALOF(a4); seen |= 1ull << (s0 + 4); }
        if (TAGOF(a5) == t) { acc += VALOF(a5); seen |= 1ull << (s0 + 5); }
        if (TAGOF(a6) == t) { acc += VALOF(a6); seen |= 1ull << (s0 + 6); }
        if (TAGOF(a7) == t) { acc += VALOF(a7); seen |= 1ull << (s0 + 7); }
      }
    }
    const bool done = !act || (seen == ~0ull);
    if (__ballot(!done) == 0ull) break;
    __builtin_amdgcn_s_sleep(1);
  }
  return acc;
}

__global__ void dec_init(int* wsi) {
  for (int k = threadIdx.x; k < WS_GI; k += NT) wsi[k] = 0;
}

__global__ void __launch_bounds__(NT, 4) dec_main(
    const float* __restrict__ enc, const float* __restrict__ hidden,
    const float* __restrict__ embed, const float* __restrict__ w_ih,
    const float* __restrict__ w_hh, const float* __restrict__ b_ih,
    const float* __restrict__ b_hh, const float* __restrict__ w_out,
    const float* __restrict__ b_out, float* __restrict__ o,
    float* __restrict__ ws) {
  const int b = blockIdx.x, tid = threadIdx.x;
  const int wave = tid >> 6, lane = tid & 63;
  const int r0 = b * ROWS;

  __shared__ __align__(16) float h_lds[512];
  __shared__ float pw_lds[NW * 48];
  __shared__ float w2_lds[48];
  __shared__ float hp_lds[48];
  __shared__ float sc_lds[1];
  __shared__ int go_lds;  /* 1 when gi table globally valid   */
  __shared__ int bf_lds;  /* (t<<6)|best                      */
  __shared__ int w1f, w2f;

  // ----------------- prologue -----------------
  if (tid < 512) h_lds[tid] = hidden[tid];
  if (tid == 0) { go_lds = 0; bf_lds = -1; w1f = 0; w2f = 0; }
  __syncthreads();  // h_lds ready

  // aux rows in registers: waves 1..12 -> W_hh row b*12+w-1; wave13 -> hp row
  float4 xa0 = {0, 0, 0, 0}, xa1 = {0, 0, 0, 0};
  float xb = 0.0f;
  if (wave >= 1 && wave <= NAUX) {
    const int j = b * NAUX + (wave - 1);
    const float* wp = w_hh + (size_t)j * 512;
    xa0 = ((const float4*)wp)[lane];
    xa1 = ((const float4*)wp)[lane + 64];
    xb = b_hh[j];
  } else if (wave == 13 && b < NV) {
    const float* wp = w_out + (size_t)b * 1024 + 512;
    xa0 = ((const float4*)wp)[lane];
    xa1 = ((const float4*)wp)[lane + 64];
    xb = b_out[b];
  }

  // gi_all[v][j] = W_ih[j].embed[v] + b_ih[j]   (480 dots per block, plain)
  for (int u = wave; u < 480; u += NW) {
    const int gl = b * 480 + u;
    const int v = gl / 1536, j = gl - v * 1536;
    const float d = wdot512(w_ih + (size_t)j * 512, embed + (size_t)v * 512);
    if (lane == 0) ws[WS_GI + (size_t)v * 1536 + j] = d + b_ih[j];
  }

  // M columns: Mv[r][lane] = W_out[lane,:512].V[row r]; lane40 = 1 (S col)
  const float* rowp = enc + (size_t)(r0 + wave * RPW) * 1024;
  float Mv[RPW];
#pragma unroll
  for (int r = 0; r < RPW; ++r) Mv[r] = (lane == 40) ? 1.0f : 0.0f;
  {
    float4 va[RPW], vb[RPW];
#pragma unroll
    for (int r = 0; r < RPW; ++r) {
      va[r] = ((const float4*)(rowp + r * 1024 + 512))[lane];
      vb[r] = ((const float4*)(rowp + r * 1024 + 512))[lane + 64];
    }
    for (int v = 0; v < NV; ++v) {
      const float* wp = w_out + (size_t)v * 1024;
      const float4 w0 = ((const float4*)wp)[lane];
      const float4 w1 = ((const float4*)wp)[lane + 64];
#pragma unroll
      for (int r = 0; r < RPW; ++r) {
        const float s = wred(dot8(va[r], vb[r], w0, w1));
        if (lane == v) Mv[r] = s;
      }
    }
  }
  // K rows into registers (re-uses the va/vb register budget; R6-validated)
  float4 ka[RPW], kb[RPW];
#pragma unroll
  for (int r = 0; r < RPW; ++r) {
    ka[r] = ((const float4*)(rowp + r * 1024))[lane];
    kb[r] = ((const float4*)(rowp + r * 1024))[lane + 64];
  }

  // gh(h0) -> buf 0, tag 1 (self-announcing)
  if (wave >= 1 && wave <= NAUX) {
    const float4 hh0 = ((const float4*)h_lds)[lane];
    const float4 hh1 = ((const float4*)h_lds)[lane + 64];
    const float d = wred(dot8(xa0, xa1, hh0, hh1));
    if (lane == 0)
      st_tag(&ws[WS_GHT + 2 * (b * NAUX + (wave - 1))], d + xb, 1);
  }
  __syncthreads();
  // release: flushes the plain gi stores to the coherence point + marker
  if (tid == 0) st_tag_rel(&ws[WS_RDY + 2 * b], 0.0f, 1);

  // ----------------- main loop -----------------
  int eos_reg = -1;  /* block0/wave0/lane0 only */
  float pz[RPW];
#pragma unroll
  for (int r = 0; r < RPW; ++r) pz[r] = 0.0f;
  float* attn = o + (size_t)MAXLEN * NV + 1;

  for (int t = 0; t <= MAXLEN; ++t) {
    if (wave == 0) {
      if (t == 0) {
        if (lane == 0) st_lds_rel(&bf_lds, EOS_IDX);  /* (0<<6)|EOS */
      } else {
        float* rb = ws + WS_REC + (size_t)(t & 1) * (NB * RSTRIDE);
        const float acc = sweep64(rb, t, lane);  // srcs 0-63
        while (ld_lds_acq(&w2f) < t) __builtin_amdgcn_s_sleep(1);
        while (ld_lds_acq(&w1f) < t) __builtin_amdgcn_s_sleep(1);
        const float cs = acc + ((lane < 41) ? w2_lds[lane] : 0.0f);
        const float hp = (lane < NV) ? hp_lds[lane] : 0.0f;
        const float S = __shfl(cs, NV, 64);
        const float ov = cs * (1.0f / S) + hp;
        unsigned long long key = 0ull;
        if (lane < NV) {
          unsigned u_ = __float_as_uint(ov);
          u_ = (u_ & 0x80000000u) ? ~u_ : (u_ | 0x80000000u);
          key = ((unsigned long long)u_ << 32) | (unsigned)(~lane);
        }
#pragma unroll
        for (int m = 32; m > 0; m >>= 1) {
          const unsigned long long k2 = __shfl_xor(key, m, 64);
          if (k2 > key) key = k2;
        }
        const int best = (int)(~(unsigned)key);
        if (b == 0 && lane < NV) o[(size_t)(t - 1) * NV + lane] = ov;
        if (lane == 0) {
          sc_lds[0] = S;
          if (b == 0) {
            if (best == EOS_IDX && eos_reg < 0) eos_reg = t - 1;
            if (t == MAXLEN)
              o[(size_t)MAXLEN * NV] =
                  (eos_reg < 0) ? (float)MAXLEN : (float)eos_reg;
          }
          st_lds_rel(&bf_lds, (t << 6) | best);
        }
      }
    } else if (wave == 1) {
      if (t == 0) {
        // ready detect: gates gi reads (and publishes nothing global)
        bool ok = false;
        for (;;) {
          if (!ok)
            ok = (TAGOF(ld_tag(&ws[WS_RDY + 2 * lane])) == 1) &&
                 (TAGOF(ld_tag(&ws[WS_RDY + 2 * (lane + 64)])) == 1);
          if (__ballot(!ok) == 0ull) break;
          __builtin_amdgcn_s_sleep(1);
        }
        if (lane == 0) st_lds_rel(&go_lds, 1);
      } else {
        // hp sticky poll (40 tagged entries)
        float* hpb = ws + WS_HP + (size_t)(t & 1) * HSTRIDE;
        bool ok = (lane >= NV);
        float hv = 0.0f;
        for (;;) {
          if (!ok) {
            const u64 a = ld_tag(&hpb[2 * lane]);
            if (TAGOF(a) == t) { hv = VALOF(a); ok = true; }
          }
          if (__ballot(!ok) == 0ull) break;
          __builtin_amdgcn_s_sleep(1);
        }
        if (lane < NV) hp_lds[lane] = hv;
        if (lane == 0) st_lds_rel(&w1f, t);
      }
    } else if (wave == 2) {
      if (t >= 1) {
        float* rb = ws + WS_REC + (size_t)(t & 1) * (NB * RSTRIDE);
        const float acc = sweep64(rb + 64 * RSTRIDE, t, lane);  // srcs 64-127
        if (lane < 41) w2_lds[lane] = acc;
        if (lane == 0) st_lds_rel(&w2f, t);
      }
    } else if (wave >= 8 && t < MAXLEN) {
      // ---- GRU waves: self-tagged gh poll (overlaps the whole decide) ----
      const int j = tid - 512;
      float* gb = ws + WS_GHT + (size_t)(t & 1) * 3072;
      float ghr, ghz, ghn;
      for (;;) {
        const u64 a0 = ld_tag(&gb[2 * j]);
        const u64 a1 = ld_tag(&gb[2 * (j + 512)]);
        const u64 a2 = ld_tag(&gb[2 * (j + 1024)]);
        if (TAGOF(a0) == t + 1 && TAGOF(a1) == t + 1 && TAGOF(a2) == t + 1) {
          ghr = VALOF(a0); ghz = VALOF(a1); ghn = VALOF(a2);
          break;
        }
        __builtin_amdgcn_s_sleep(1);
      }
      if (t == 0)
        while (ld_lds_acq(&go_lds) < 1) __builtin_amdgcn_s_sleep(1);
      int bf;
      while (((bf = ld_lds_acq(&bf_lds)) >> 6) < t) __builtin_amdgcn_s_sleep(1);
      const float* gi = ws + WS_GI + (size_t)(bf & 63) * 1536;
      const float gir = gi[j], giz = gi[j + 512], gin = gi[j + 1024];
      const float r_ = 1.0f / (1.0f + expf(-(gir + ghr)));
      const float z_ = 1.0f / (1.0f + expf(-(giz + ghz)));
      const float n_ = tanhf(gin + r_ * ghn);
      h_lds[j] = (1.0f - z_) * n_ + z_ * h_lds[j];
    }
    __syncthreads();  // barrier A: h_t, sc_lds ready

    // store previous step's normalized attention weights (p in regs)
    if (t > 0 && lane < RPW) {
      float pv = pz[0];
#pragma unroll
      for (int r = 1; r < RPW; ++r) pv = (lane == r) ? pz[r] : pv;
      attn[(size_t)(t - 1) * TENC + r0 + wave * RPW + lane] =
          pv * (1.0f / sc_lds[0]);
    }
    if (t == MAXLEN) break;

    // ---- dots: K in registers, h in LDS, aux rows in regs ----
    {
      const float4 hh0 = ((const float4*)h_lds)[lane];
      const float4 hh1 = ((const float4*)h_lds)[lane + 64];
      float dsum[RPW];
#pragma unroll
      for (int r = 0; r < RPW; ++r) dsum[r] = dot8(ka[r], kb[r], hh0, hh1);
#pragma unroll
      for (int r = 0; r < RPW; ++r) dsum[r] = wred(dsum[r]);
      float fold = 0.0f;
#pragma unroll
      for (int r = 0; r < RPW; ++r) {
        const float p = expf(dsum[r] * SCALE);
        pz[r] = p;
        fold += p * Mv[r];
      }
      if (lane < 41) pw_lds[wave * 48 + lane] = fold;
      if (wave >= 1 && wave <= NAUX) {  // gh row for step t+1 -> tag t+2
        const float d = wred(dot8(xa0, xa1, hh0, hh1));
        if (lane == 0)
          st_tag(&ws[WS_GHT + (size_t)((t + 1) & 1) * 3072 +
                     2 * (b * NAUX + (wave - 1))],
                 d + xb, t + 2);
      } else if (wave == 13 && b < NV) {  // hp row -> tag t+1
        const float d = wred(dot8(xa0, xa1, hh0, hh1));
        if (lane == 0)
          st_tag(&ws[WS_HP + (size_t)((t + 1) & 1) * HSTRIDE + 2 * b],
                 d + xb, t + 1);
      }
    }
    __syncthreads();  // barrier C: pw complete

    // ---- wave0: reduce 16 wave-partials, push tagged record (no waits) ----
    if (wave == 0 && lane < 41) {
      float s = 0.0f;
#pragma unroll
      for (int w2 = 0; w2 < NW; ++w2) s += pw_lds[w2 * 48 + lane];
      st_tag(&ws[WS_REC + (size_t)((t + 1) & 1) * (NB * RSTRIDE) +
                 b * RSTRIDE + 2 * lane],
             s, t + 1);
    }
  }
}

extern "C" void kernel_launch(void* const* d_in, const int* in_sizes, int n_in,
                              void* d_out, int out_size, void* d_ws,
                              size_t ws_size, hipStream_t stream) {
  const float* enc    = (const float*)d_in[0];
  const float* hidden = (const float*)d_in[1];
  const float* embed  = (const float*)d_in[2];
  const float* w_ih   = (const float*)d_in[3];
  const float* w_hh   = (const float*)d_in[4];
  const float* b_ih   = (const float*)d_in[5];
  const float* b_hh   = (const float*)d_in[6];
  const float* w_out  = (const float*)d_in[7];
  const float* b_out  = (const float*)d_in[8];
  float* out = (float*)d_out;
  float* ws  = (float*)d_ws;

  dec_init<<<dim3(1), dim3(NT), 0, stream>>>((int*)d_ws);
  dec_main<<<dim3(NB), dim3(NT), 0, stream>>>(enc, hidden, embed, w_ih, w_hh,
                                              b_ih, b_hh, w_out, b_out, out,
                                              ws);
}

// Round 6
// 7707.118 us; speedup vs baseline: 1.0021x; 1.0021x over previous
//
#include <hip/hip_runtime.h>
#include <math.h>

// ---------------------------------------------------------------------------
// TDS decoder R10: 256 persistent blocks x 1024 threads (R4 workload shape)
// + tagged single-writer protocol (R9) + spill-proof register budget.
//  - Producer: after barrier C, wave0 pushes its 41 fold-partials as {f32,tag}
//    8B atomics in ONE store instruction. No ack wait, no release counter,
//    no zero pass.
//  - Consumer: detection+gather fused, sticky-mask sweeps. 4 parallel sweep
//    waves (64 srcs each) + hp wave, combined via LDS; waves 1-7 were idle
//    during decide anyway.
//  - gh rows self-tagged (2-buf): GRU waves poll their 3 entries directly.
//  - RPW=2: K/M/aux registers exactly as R4 (proven spill-free), and
//    amdgpu_waves_per_eu(4,4) pins 1 block/CU -> 128-VGPR budget so the
//    sweep temporaries cannot force loop-carried spills (R9's 31 MB/step
//    scratch round-trip was the 5x regression).
// ---------------------------------------------------------------------------

#define NV      40
#define TENC    8192
#define MAXLEN  200
#define EOS_IDX 38
#define NB      256
#define NT      1024
#define NW      16
#define ROWS    32                    /* enc rows per block                 */
#define NAUX    6                     /* gh rows per block (1536/256)       */
#define RSTRIDE 88                    /* floats per record (41x8B pad 352B) */
#define SCALE   0.04419417382415922f  /* 1/sqrt(512) */

/* ws layout (floats, all 8B-aligned) */
#define WS_RDY  0                             /* 256 x 8B = 512             */
#define WS_REC  512                           /* 2 x 256 x 88 = 45056       */
#define WS_HP   (WS_REC + 2 * NB * RSTRIDE)   /* 45568: 2 x 88 = 176        */
#define WS_GHT  (WS_HP + 2 * RSTRIDE)         /* 45744: 2 x 1536 x 2 = 6144 */
#define WS_GI   (WS_GHT + 2 * 3072)           /* 51888: 40 x 1536           */
/* total = 51888 + 61440 = 113328 floats (453 KB) */

typedef unsigned long long u64;

__device__ __forceinline__ void st_tag(float* p, float v, int tag) {
  const u64 x = ((u64)(unsigned)tag << 32) | (u64)__float_as_uint(v);
  __hip_atomic_store((u64*)p, x, __ATOMIC_RELAXED, __HIP_MEMORY_SCOPE_AGENT);
}
__device__ __forceinline__ void st_tag_rel(float* p, float v, int tag) {
  const u64 x = ((u64)(unsigned)tag << 32) | (u64)__float_as_uint(v);
  __hip_atomic_store((u64*)p, x, __ATOMIC_RELEASE, __HIP_MEMORY_SCOPE_AGENT);
}
__device__ __forceinline__ u64 ld_tag(float* p) {
  return __hip_atomic_load((u64*)p, __ATOMIC_RELAXED, __HIP_MEMORY_SCOPE_AGENT);
}
#define TAGOF(x) ((int)(unsigned)((x) >> 32))
#define VALOF(x) __uint_as_float((unsigned)(x))

__device__ __forceinline__ int ld_lds_acq(int* p) {
  return __hip_atomic_load(p, __ATOMIC_ACQUIRE, __HIP_MEMORY_SCOPE_WORKGROUP);
}
__device__ __forceinline__ void st_lds_rel(int* p, int v) {
  __hip_atomic_store(p, v, __ATOMIC_RELEASE, __HIP_MEMORY_SCOPE_WORKGROUP);
}

__device__ __forceinline__ float wred(float s) {
#pragma unroll
  for (int o = 32; o > 0; o >>= 1) s += __shfl_xor(s, o, 64);
  return s;
}
__device__ __forceinline__ float dot8(float4 a0, float4 a1, float4 b0,
                                      float4 b1) {
  return a0.x * b0.x + a0.y * b0.y + a0.z * b0.z + a0.w * b0.w +
         a1.x * b1.x + a1.y * b1.y + a1.z * b1.z + a1.w * b1.w;
}
__device__ __forceinline__ float wdot512(const float* __restrict__ a,
                                         const float* __restrict__ b) {
  const int l = threadIdx.x & 63;
  const float4 a0 = ((const float4*)a)[l];
  const float4 a1 = ((const float4*)a)[l + 64];
  const float4 b0 = ((const float4*)b)[l];
  const float4 b1 = ((const float4*)b)[l + 64];
  return wred(dot8(a0, a1, b0, b1));
}

// Sticky-mask pipelined sweep over 64 sources for this lane's column.
__device__ __forceinline__ float sweep64(float* rb, int t, int lane) {
  float acc = 0.0f;
  u64 seen = 0;
  const bool act = (lane < 41);
  for (;;) {
    const u64 want = ~seen;
    if (act) {
#pragma unroll
      for (int g = 0; g < 8; ++g) {
        const int s0 = g * 8;
        u64 a0 = 0, a1 = 0, a2 = 0, a3 = 0, a4 = 0, a5 = 0, a6 = 0, a7 = 0;
        if ((want >> (s0 + 0)) & 1) a0 = ld_tag(&rb[(s0 + 0) * RSTRIDE + 2 * lane]);
        if ((want >> (s0 + 1)) & 1) a1 = ld_tag(&rb[(s0 + 1) * RSTRIDE + 2 * lane]);
        if ((want >> (s0 + 2)) & 1) a2 = ld_tag(&rb[(s0 + 2) * RSTRIDE + 2 * lane]);
        if ((want >> (s0 + 3)) & 1) a3 = ld_tag(&rb[(s0 + 3) * RSTRIDE + 2 * lane]);
        if ((want >> (s0 + 4)) & 1) a4 = ld_tag(&rb[(s0 + 4) * RSTRIDE + 2 * lane]);
        if ((want >> (s0 + 5)) & 1) a5 = ld_tag(&rb[(s0 + 5) * RSTRIDE + 2 * lane]);
        if ((want >> (s0 + 6)) & 1) a6 = ld_tag(&rb[(s0 + 6) * RSTRIDE + 2 * lane]);
        if ((want >> (s0 + 7)) & 1) a7 = ld_tag(&rb[(s0 + 7) * RSTRIDE + 2 * lane]);
        if (TAGOF(a0) == t) { acc += VALOF(a0); seen |= 1ull << (s0 + 0); }
        if (TAGOF(a1) == t) { acc += VALOF(a1); seen |= 1ull << (s0 + 1); }
        if (TAGOF(a2) == t) { acc += VALOF(a2); seen |= 1ull << (s0 + 2); }
        if (TAGOF(a3) == t) { acc += VALOF(a3); seen |= 1ull << (s0 + 3); }
        if (TAGOF(a4) == t) { acc += VALOF(a4); seen |= 1ull << (s0 + 4); }
        if (TAGOF(a5) == t) { acc += VALOF(a5); seen |= 1ull << (s0 + 5); }
        if (TAGOF(a6) == t) { acc += VALOF(a6); seen |= 1ull << (s0 + 6); }
        if (TAGOF(a7) == t) { acc += VALOF(a7); seen |= 1ull << (s0 + 7); }
      }
    }
    const bool done = !act || (seen == ~0ull);
    if (__ballot(!done) == 0ull) break;
    __builtin_amdgcn_s_sleep(1);
  }
  return acc;
}

__global__ void dec_init(int* wsi) {
  for (int k = threadIdx.x; k < WS_GI; k += NT) wsi[k] = 0;
}

__global__ void __launch_bounds__(NT)
    __attribute__((amdgpu_waves_per_eu(4, 4))) dec_main(
    const float* __restrict__ enc, const float* __restrict__ hidden,
    const float* __restrict__ embed, const float* __restrict__ w_ih,
    const float* __restrict__ w_hh, const float* __restrict__ b_ih,
    const float* __restrict__ b_hh, const float* __restrict__ w_out,
    const float* __restrict__ b_out, float* __restrict__ o,
    float* __restrict__ ws) {
  const int b = blockIdx.x, tid = threadIdx.x;
  const int wave = tid >> 6, lane = tid & 63;
  const int r0 = b * ROWS;

  __shared__ __align__(16) float h_lds[512];
  __shared__ float pw_lds[NW * 48];
  __shared__ float sw_lds[3][48];
  __shared__ float hp_lds[48];
  __shared__ float sc_lds[1];
  __shared__ int go_lds;   /* 1 when gi table globally valid  */
  __shared__ int bf_lds;   /* (t<<6)|best                     */
  __shared__ int sfl[4];   /* sweep/hp helper flags           */

  // ----------------- prologue -----------------
  if (tid < 512) h_lds[tid] = hidden[tid];
  if (tid == 0) { go_lds = 0; bf_lds = -1; }
  if (tid < 4) sfl[tid] = 0;
  __syncthreads();  // h_lds ready

  // gi_all[v][j] = W_ih[j].embed[v] + b_ih[j]  (240 dots per block)
  for (int u = wave; u < 240; u += NW) {
    const int gl = b * 240 + u;
    const int v = gl / 1536, j = gl - v * 1536;
    const float d = wdot512(w_ih + (size_t)j * 512, embed + (size_t)v * 512);
    if (lane == 0) ws[WS_GI + (size_t)v * 1536 + j] = d + b_ih[j];
  }

  // --- register-resident operands (R4 shape) ---
  const float* k0p = enc + (size_t)(r0 + 2 * wave) * 1024;
  const float4 k0a = ((const float4*)k0p)[lane];
  const float4 k0b = ((const float4*)k0p)[lane + 64];
  const float4 k1a = ((const float4*)(k0p + 1024))[lane];
  const float4 k1b = ((const float4*)(k0p + 1024))[lane + 64];

  // M columns: Mr0/Mr1 = W_out[lane,:512].V[row0/1]; lane40 = 1 (S column)
  float Mr0 = (lane == 40) ? 1.0f : 0.0f, Mr1 = Mr0;
  {
    const float* v0p = k0p + 512;
    const float4 va0 = ((const float4*)v0p)[lane];
    const float4 va1 = ((const float4*)v0p)[lane + 64];
    const float4 vb0 = ((const float4*)(v0p + 1024))[lane];
    const float4 vb1 = ((const float4*)(v0p + 1024))[lane + 64];
    for (int v = 0; v < NV; ++v) {
      const float* wp = w_out + (size_t)v * 1024;
      const float4 w0 = ((const float4*)wp)[lane];
      const float4 w1 = ((const float4*)wp)[lane + 64];
      const float sa = wred(dot8(va0, va1, w0, w1));
      const float sb = wred(dot8(vb0, vb1, w0, w1));
      if (lane == v) { Mr0 = sa; Mr1 = sb; }
    }
  }
  // aux row: waves 1-6 -> W_hh row b*6+wave-1; wave 7 (b<NV) -> W_out hp row
  float4 xa0 = {0, 0, 0, 0}, xa1 = {0, 0, 0, 0};
  float xb = 0.0f;
  if (wave >= 1 && wave <= NAUX) {
    const int j = b * NAUX + (wave - 1);
    const float* wp = w_hh + (size_t)j * 512;
    xa0 = ((const float4*)wp)[lane];
    xa1 = ((const float4*)wp)[lane + 64];
    xb = b_hh[j];
  } else if (wave == 7 && b < NV) {
    const float* wp = w_out + (size_t)b * 1024 + 512;
    xa0 = ((const float4*)wp)[lane];
    xa1 = ((const float4*)wp)[lane + 64];
    xb = b_out[b];
  }

  // gh(h0) -> buf 0, tag 1 (self-announcing)
  if (wave >= 1 && wave <= NAUX) {
    const float4 hh0 = ((const float4*)h_lds)[lane];
    const float4 hh1 = ((const float4*)h_lds)[lane + 64];
    const float d = wred(dot8(xa0, xa1, hh0, hh1));
    if (lane == 0)
      st_tag(&ws[WS_GHT + 2 * (b * NAUX + (wave - 1))], d + xb, 1);
  }
  __syncthreads();  /* drain all prologue stores */
  // release: flushes the plain gi stores to the coherence point + marker
  if (tid == 0) st_tag_rel(&ws[WS_RDY + 2 * b], 0.0f, 1);

  // ----------------- main loop -----------------
  int eos_reg = -1;            /* block0/wave0/lane0 only */
  float p0 = 0.0f, p1 = 0.0f;  /* this wave's unnormalized attention wts */
  float* attn = o + (size_t)MAXLEN * NV + 1;

  for (int t = 0; t <= MAXLEN; ++t) {
    float* rb = ws + WS_REC + (size_t)(t & 1) * (NB * RSTRIDE);
    if (wave == 0) {
      if (t == 0) {
        if (lane == 0) st_lds_rel(&bf_lds, EOS_IDX);  /* (0<<6)|EOS */
      } else {
        float acc = sweep64(rb, t, lane);  // srcs 0-63
        while (ld_lds_acq(&sfl[0]) < t) __builtin_amdgcn_s_sleep(1);
        while (ld_lds_acq(&sfl[1]) < t) __builtin_amdgcn_s_sleep(1);
        while (ld_lds_acq(&sfl[2]) < t) __builtin_amdgcn_s_sleep(1);
        while (ld_lds_acq(&sfl[3]) < t) __builtin_amdgcn_s_sleep(1);
        float cs = acc;
        if (lane < 41)
          cs += sw_lds[0][lane] + sw_lds[1][lane] + sw_lds[2][lane];
        const float hp = (lane < NV) ? hp_lds[lane] : 0.0f;
        const float S = __shfl(cs, NV, 64);
        const float ov = cs * (1.0f / S) + hp;
        unsigned long long key = 0ull;
        if (lane < NV) {
          unsigned u_ = __float_as_uint(ov);
          u_ = (u_ & 0x80000000u) ? ~u_ : (u_ | 0x80000000u);
          key = ((unsigned long long)u_ << 32) | (unsigned)(~lane);
        }
#pragma unroll
        for (int m = 32; m > 0; m >>= 1) {
          const unsigned long long k2 = __shfl_xor(key, m, 64);
          if (k2 > key) key = k2;
        }
        const int best = (int)(~(unsigned)key);
        if (b == 0 && lane < NV) o[(size_t)(t - 1) * NV + lane] = ov;
        if (lane == 0) {
          sc_lds[0] = S;
          if (b == 0) {
            if (best == EOS_IDX && eos_reg < 0) eos_reg = t - 1;
            if (t == MAXLEN)
              o[(size_t)MAXLEN * NV] =
                  (eos_reg < 0) ? (float)MAXLEN : (float)eos_reg;
          }
          st_lds_rel(&bf_lds, (t << 6) | best);
        }
      }
    } else if (wave >= 1 && wave <= 3) {
      if (t == 0) {
        if (wave == 1) {  // ready detect: gates gi reads
          bool ok = false;
          for (;;) {
            if (!ok)
              ok = (TAGOF(ld_tag(&ws[WS_RDY + 2 * lane])) == 1) &&
                   (TAGOF(ld_tag(&ws[WS_RDY + 2 * (lane + 64)])) == 1) &&
                   (TAGOF(ld_tag(&ws[WS_RDY + 2 * (lane + 128)])) == 1) &&
                   (TAGOF(ld_tag(&ws[WS_RDY + 2 * (lane + 192)])) == 1);
            if (__ballot(!ok) == 0ull) break;
            __builtin_amdgcn_s_sleep(1);
          }
          if (lane == 0) st_lds_rel(&go_lds, 1);
        }
      } else {
        const float acc = sweep64(rb + (size_t)(64 * wave) * RSTRIDE, t, lane);
        if (lane < 41) sw_lds[wave - 1][lane] = acc;
        if (lane == 0) st_lds_rel(&sfl[wave - 1], t);
      }
    } else if (wave == 4) {
      if (t >= 1) {  // hp sticky poll (40 tagged entries)
        float* hpb = ws + WS_HP + (size_t)(t & 1) * RSTRIDE;
        bool ok = (lane >= NV);
        float hv = 0.0f;
        for (;;) {
          if (!ok) {
            const u64 a = ld_tag(&hpb[2 * lane]);
            if (TAGOF(a) == t) { hv = VALOF(a); ok = true; }
          }
          if (__ballot(!ok) == 0ull) break;
          __builtin_amdgcn_s_sleep(1);
        }
        if (lane < NV) hp_lds[lane] = hv;
        if (lane == 0) st_lds_rel(&sfl[3], t);
      }
    } else if (wave >= 8 && t < MAXLEN) {
      // ---- GRU waves: self-tagged gh poll (overlaps the whole decide) ----
      const int j = tid - 512;
      float* gb = ws + WS_GHT + (size_t)(t & 1) * 3072;
      float ghr, ghz, ghn;
      for (;;) {
        const u64 a0 = ld_tag(&gb[2 * j]);
        const u64 a1 = ld_tag(&gb[2 * (j + 512)]);
        const u64 a2 = ld_tag(&gb[2 * (j + 1024)]);
        if (TAGOF(a0) == t + 1 && TAGOF(a1) == t + 1 && TAGOF(a2) == t + 1) {
          ghr = VALOF(a0); ghz = VALOF(a1); ghn = VALOF(a2);
          break;
        }
        __builtin_amdgcn_s_sleep(1);
      }
      if (t == 0)
        while (ld_lds_acq(&go_lds) < 1) __builtin_amdgcn_s_sleep(1);
      int bf;
      while (((bf = ld_lds_acq(&bf_lds)) >> 6) < t) __builtin_amdgcn_s_sleep(1);
      const float* gi = ws + WS_GI + (size_t)(bf & 63) * 1536;
      const float gir = gi[j], giz = gi[j + 512], gin = gi[j + 1024];
      const float r_ = 1.0f / (1.0f + expf(-(gir + ghr)));
      const float z_ = 1.0f / (1.0f + expf(-(giz + ghz)));
      const float n_ = tanhf(gin + r_ * ghn);
      h_lds[j] = (1.0f - z_) * n_ + z_ * h_lds[j];
    }
    __syncthreads();  // barrier A: h_t, sc_lds ready

    // store previous step's normalized attention weights (p in regs)
    if (t > 0 && lane < 2)
      attn[(size_t)(t - 1) * TENC + r0 + 2 * wave + lane] =
          (lane ? p1 : p0) * (1.0f / sc_lds[0]);
    if (t == MAXLEN) break;

    // ---- dots: all operands in registers / LDS ----
    {
      const float4 hh0 = ((const float4*)h_lds)[lane];
      const float4 hh1 = ((const float4*)h_lds)[lane + 64];
      const float d0 = wred(dot8(k0a, k0b, hh0, hh1));
      const float d1 = wred(dot8(k1a, k1b, hh0, hh1));
      p0 = expf(d0 * SCALE);
      p1 = expf(d1 * SCALE);
      if (lane < 41) pw_lds[wave * 48 + lane] = p0 * Mr0 + p1 * Mr1;
      if (wave >= 1 && wave <= NAUX) {  // gh row for step t+1 -> tag t+2
        const float d = wred(dot8(xa0, xa1, hh0, hh1));
        if (lane == 0)
          st_tag(&ws[WS_GHT + (size_t)((t + 1) & 1) * 3072 +
                     2 * (b * NAUX + (wave - 1))],
                 d + xb, t + 2);
      } else if (wave == 7 && b < NV) {  // hp row -> tag t+1
        const float d = wred(dot8(xa0, xa1, hh0, hh1));
        if (lane == 0)
          st_tag(&ws[WS_HP + (size_t)((t + 1) & 1) * RSTRIDE + 2 * b],
                 d + xb, t + 1);
      }
    }
    __syncthreads();  // barrier C: pw complete

    // ---- wave0: reduce 16 wave-partials, push tagged record (no waits) ----
    if (wave == 0 && lane < 41) {
      float s = 0.0f;
#pragma unroll
      for (int w2 = 0; w2 < NW; ++w2) s += pw_lds[w2 * 48 + lane];
      st_tag(&ws[WS_REC + (size_t)((t + 1) & 1) * (NB * RSTRIDE) +
                 b * RSTRIDE + 2 * lane],
             s, t + 1);
    }
  }
}

extern "C" void kernel_launch(void* const* d_in, const int* in_sizes, int n_in,
                              void* d_out, int out_size, void* d_ws,
                              size_t ws_size, hipStream_t stream) {
  const float* enc    = (const float*)d_in[0];
  const float* hidden = (const float*)d_in[1];
  const float* embed  = (const float*)d_in[2];
  const float* w_ih   = (const float*)d_in[3];
  const float* w_hh   = (const float*)d_in[4];
  const float* b_ih   = (const float*)d_in[5];
  const float* b_hh   = (const float*)d_in[6];
  const float* w_out  = (const float*)d_in[7];
  const float* b_out  = (const float*)d_in[8];
  float* out = (float*)d_out;
  float* ws  = (float*)d_ws;

  dec_init<<<dim3(1), dim3(NT), 0, stream>>>((int*)d_ws);
  dec_main<<<dim3(NB), dim3(NT), 0, stream>>>(enc, hidden, embed, w_ih, w_hh,
                                              b_ih, b_hh, w_out, b_out, out,
                                              ws);
}

// Round 7
// 1506.388 us; speedup vs baseline: 5.1272x; 5.1163x over previous
//
#include <hip/hip_runtime.h>
#include <math.h>

// ---------------------------------------------------------------------------
// TDS decoder R11: R4 (verified 1507us) with the push moved OFF the critical
// path. Identical protocol (sticky counter poll, 3-slot rotation, single
// pipelined gather, 41 RMW adds + release counter per block per step); the
// only change is WHEN the reduce+adds happen:
//  - waves 1-15: write fold partial to pw_lds, release-inc an LDS counter,
//    then do aux/zero work (as R4).
//  - wave0: computes its own fold, acquire-spins on the LDS counter (intra-CU,
//    cheap), reduces 16 partials, issues the 41 atomicAdds -- all BEFORE
//    barrier C. The RMW acks drain inside the barrier, overlapped with the
//    aux-dot tail of waves 1-6.
//  - post-barrier C the critical path is ONE instruction: tid0 fires the
//    release fetch_add (barrier guarantees all RMWs are performed at MALL).
//  Plus R7's harmless hp-first gather ordering.
// ---------------------------------------------------------------------------

#define NV      40
#define TENC    8192
#define MAXLEN  200
#define EOS_IDX 38
#define NB      256
#define NT      1024
#define NW      16
#define ROWS    32
#define NG      64                    /* groups of NB/NG=4 blocks           */
#define GSTRIDE 96                    /* floats per group region            */
#define GCNT    64                    /* counter col (own cacheline)        */
#define HPOFF   (NG * GSTRIDE)        /* 6144: hp line within slot          */
#define SLOT    (HPOFF + 64)          /* 6208 floats per rotation slot      */
#define SCALE   0.04419417382415922f  /* 1/sqrt(512) */

#define WS_ACC  128                   /* float[3][SLOT]                     */
#define WS_GH   (WS_ACC + 3 * SLOT)   /* 18752: float[3][1536]              */
#define WS_GI   (WS_GH + 3 * 1536)    /* 23360: float[40*1536]              */

__device__ __forceinline__ int ld_ai(int* p) {
  return __hip_atomic_load(p, __ATOMIC_RELAXED, __HIP_MEMORY_SCOPE_AGENT);
}
__device__ __forceinline__ float ld_af(float* p) {
  return __hip_atomic_load(p, __ATOMIC_RELAXED, __HIP_MEMORY_SCOPE_AGENT);
}
__device__ __forceinline__ void st_af(float* p, float v) {
  __hip_atomic_store(p, v, __ATOMIC_RELAXED, __HIP_MEMORY_SCOPE_AGENT);
}
__device__ __forceinline__ void st_ai(int* p, int v) {
  __hip_atomic_store(p, v, __ATOMIC_RELAXED, __HIP_MEMORY_SCOPE_AGENT);
}
__device__ __forceinline__ int ld_lds_acq(int* p) {
  return __hip_atomic_load(p, __ATOMIC_ACQUIRE, __HIP_MEMORY_SCOPE_WORKGROUP);
}
__device__ __forceinline__ void st_lds_rel(int* p, int v) {
  __hip_atomic_store(p, v, __ATOMIC_RELEASE, __HIP_MEMORY_SCOPE_WORKGROUP);
}
__device__ __forceinline__ void inc_lds_rel(int* p) {
  __hip_atomic_fetch_add(p, 1, __ATOMIC_RELEASE, __HIP_MEMORY_SCOPE_WORKGROUP);
}

__device__ __forceinline__ float wred(float s) {
#pragma unroll
  for (int o = 32; o > 0; o >>= 1) s += __shfl_xor(s, o, 64);
  return s;
}
__device__ __forceinline__ float dot8(float4 a0, float4 a1, float4 b0,
                                      float4 b1) {
  return a0.x * b0.x + a0.y * b0.y + a0.z * b0.z + a0.w * b0.w +
         a1.x * b1.x + a1.y * b1.y + a1.z * b1.z + a1.w * b1.w;
}
__device__ __forceinline__ float wdot512(const float* __restrict__ a,
                                         const float* __restrict__ b) {
  const int l = threadIdx.x & 63;
  const float4 a0 = ((const float4*)a)[l];
  const float4 a1 = ((const float4*)a)[l + 64];
  const float4 b0 = ((const float4*)b)[l];
  const float4 b1 = ((const float4*)b)[l + 64];
  return wred(dot8(a0, a1, b0, b1));
}

__global__ void dec_init(int* wsi) {
  for (int k = threadIdx.x; k < WS_GH; k += NT) wsi[k] = 0;
}

__global__ void __launch_bounds__(NT, 4) dec_main(
    const float* __restrict__ enc, const float* __restrict__ hidden,
    const float* __restrict__ embed, const float* __restrict__ w_ih,
    const float* __restrict__ w_hh, const float* __restrict__ b_ih,
    const float* __restrict__ b_hh, const float* __restrict__ w_out,
    const float* __restrict__ b_out, float* __restrict__ o,
    float* __restrict__ ws) {
  const int b = blockIdx.x, tid = threadIdx.x;
  const int wave = tid >> 6, lane = tid & 63;
  const int g = b & (NG - 1);
  const int r0 = b * ROWS;

  __shared__ __align__(16) float h_lds[512];
  __shared__ float pw_lds[NW * 48];
  __shared__ float sc_lds[1];
  __shared__ int go_lds;  // t+1 when step-t inputs are at the MALL
  __shared__ int bf_lds;  // (t<<6)|best
  __shared__ int pwc;     // monotonic: waves 1-15 inc once per dots phase

  // ----------------- prologue -----------------
  if (tid < 512) h_lds[tid] = hidden[tid];
  if (tid == 0) { go_lds = 0; bf_lds = -1; pwc = 0; }

  // gi_all[v][j] = W_ih[j].embed[v] + b_ih[j]  (240 dots per block)
  for (int u = wave; u < 240; u += NW) {
    const int gl = b * 240 + u;
    const int v = gl / 1536, j = gl - v * 1536;
    const float d = wdot512(w_ih + (size_t)j * 512, embed + (size_t)v * 512);
    if (lane == 0) ws[WS_GI + (size_t)v * 1536 + j] = d + b_ih[j];
  }
  // gh(h0) -> slot 2  (waves 0-5, one row each)
  for (int jr = wave; jr < 6; jr += NW) {
    const int j = b * 6 + jr;
    const float d = wdot512(w_hh + (size_t)j * 512, hidden);
    if (lane == 0) st_af(&ws[WS_GH + 2 * 1536 + j], d + b_hh[j]);
  }
  __syncthreads();  // drain stores
  if (tid == 0)
    __hip_atomic_fetch_add((int*)(ws + WS_ACC + 2 * SLOT + g * GSTRIDE + GCNT),
                           1, __ATOMIC_RELEASE, __HIP_MEMORY_SCOPE_AGENT);

  // --- register-resident operands ---
  const float* k0p = enc + (size_t)(r0 + 2 * wave) * 1024;
  const float4 k0a = ((const float4*)k0p)[lane];
  const float4 k0b = ((const float4*)k0p)[lane + 64];
  const float4 k1a = ((const float4*)(k0p + 1024))[lane];
  const float4 k1b = ((const float4*)(k0p + 1024))[lane + 64];

  // M columns: Mr0/Mr1 = W_out[lane,:512].V[row0/1]; lane40 = 1 (S column)
  float Mr0 = (lane == 40) ? 1.0f : 0.0f, Mr1 = Mr0;
  {
    const float* v0p = k0p + 512;
    const float4 va0 = ((const float4*)v0p)[lane];
    const float4 va1 = ((const float4*)v0p)[lane + 64];
    const float4 vb0 = ((const float4*)(v0p + 1024))[lane];
    const float4 vb1 = ((const float4*)(v0p + 1024))[lane + 64];
    for (int v = 0; v < NV; ++v) {
      const float* wp = w_out + (size_t)v * 1024;
      const float4 w0 = ((const float4*)wp)[lane];
      const float4 w1 = ((const float4*)wp)[lane + 64];
      const float sa = wred(dot8(va0, va1, w0, w1));
      const float sb = wred(dot8(vb0, vb1, w0, w1));
      if (lane == v) { Mr0 = sa; Mr1 = sb; }
    }
  }
  // aux row: waves 1-6 -> W_hh row b*6+wave-1; wave 7 (b in 1..40) -> W_out hp
  float4 xa0 = {0, 0, 0, 0}, xa1 = {0, 0, 0, 0};
  float xb = 0.0f;
  if (wave >= 1 && wave <= 6) {
    const int j = b * 6 + (wave - 1);
    const float* wp = w_hh + (size_t)j * 512;
    xa0 = ((const float4*)wp)[lane];
    xa1 = ((const float4*)wp)[lane + 64];
    xb = b_hh[j];
  } else if (wave == 7 && b >= 1 && b <= NV) {
    const float* wp = w_out + (size_t)(b - 1) * 1024 + 512;
    xa0 = ((const float4*)wp)[lane];
    xa1 = ((const float4*)wp)[lane + 64];
    xb = b_out[b - 1];
  }

  // ----------------- main loop -----------------
  int eos_reg = -1;              // block0/wave0/lane0 only
  float p0 = 0.0f, p1 = 0.0f;    // this wave's attention weights (unnorm.)
  float* attn = o + (size_t)MAXLEN * NV + 1;

  for (int t = 0; t <= MAXLEN; ++t) {
    if (wave == 0) {
      float* accs = ws + WS_ACC + ((t + 2) % 3) * SLOT;
      {  // poll all NG counters (sticky per lane)
        int* cp = (int*)(accs + lane * GSTRIDE + GCNT);
        bool ok = false;
        for (;;) {
          if (!ok) ok = (ld_ai(cp) >= NB / NG);
          if (__ballot(!ok) == 0ull) break;
          __builtin_amdgcn_s_sleep(1);
        }
      }
      if (lane == 0) st_lds_rel(&go_lds, t + 1);  // GRU waves may start gh
      if (t > 0) {
        // hp first (in-order vmcnt: result lands after one latency)
        const float hp = (lane < NV) ? ld_af(&accs[HPOFF + lane]) : 0.0f;
        // gather 64 group partials (4 chains, all loads pipelined)
        float c0 = 0, c1 = 0, c2 = 0, c3 = 0;
#pragma unroll
        for (int q = 0; q < NG / 4; ++q) {
          c0 += ld_af(&accs[(4 * q + 0) * GSTRIDE + lane]);
          c1 += ld_af(&accs[(4 * q + 1) * GSTRIDE + lane]);
          c2 += ld_af(&accs[(4 * q + 2) * GSTRIDE + lane]);
          c3 += ld_af(&accs[(4 * q + 3) * GSTRIDE + lane]);
        }
        const float cs = (c0 + c1) + (c2 + c3);
        const float S = __shfl(cs, NV, 64);
        const float ov = cs * (1.0f / S) + hp;
        unsigned long long key = 0ull;
        if (lane < NV) {
          unsigned u = __float_as_uint(ov);
          u = (u & 0x80000000u) ? ~u : (u | 0x80000000u);
          key = ((unsigned long long)u << 32) | (unsigned)(~lane);
        }
#pragma unroll
        for (int m = 32; m > 0; m >>= 1) {
          const unsigned long long k2 = __shfl_xor(key, m, 64);
          if (k2 > key) key = k2;
        }
        const int best = (int)(~(unsigned)key);
        if (b == 0 && lane < NV) o[(size_t)(t - 1) * NV + lane] = ov;
        if (lane == 0) {
          sc_lds[0] = S;
          if (b == 0) {
            if (best == EOS_IDX && eos_reg < 0) eos_reg = t - 1;
            if (t == MAXLEN)
              o[(size_t)MAXLEN * NV] =
                  (eos_reg < 0) ? (float)MAXLEN : (float)eos_reg;
          }
          st_lds_rel(&bf_lds, (t << 6) | best);
        }
      } else if (lane == 0) {
        st_lds_rel(&bf_lds, EOS_IDX);  // (0<<6)|EOS
      }
    } else if (wave >= 8 && t < MAXLEN) {
      // ---- GRU waves: gh loads overlap wave0's decide ----
      const int j = tid - 512;
      while (ld_lds_acq(&go_lds) < t + 1) __builtin_amdgcn_s_sleep(1);
      float* ghs = ws + WS_GH + ((t + 2) % 3) * 1536;
      const float ghr = ld_af(&ghs[j]);
      const float ghz = ld_af(&ghs[j + 512]);
      const float ghn = ld_af(&ghs[j + 1024]);
      int bf;
      while (((bf = ld_lds_acq(&bf_lds)) >> 6) < t) __builtin_amdgcn_s_sleep(1);
      const float* gi = ws + WS_GI + (size_t)(bf & 63) * 1536;
      const float gir = gi[j], giz = gi[j + 512], gin = gi[j + 1024];
      const float r = 1.0f / (1.0f + expf(-(gir + ghr)));
      const float z = 1.0f / (1.0f + expf(-(giz + ghz)));
      const float n = tanhf(gin + r * ghn);
      h_lds[j] = (1.0f - z) * n + z * h_lds[j];
    }
    __syncthreads();  // barrier A: h_t, sc_lds ready

    // store previous step's normalized attention weights (p in regs)
    if (t > 0 && lane < 2)
      attn[(size_t)(t - 1) * TENC + r0 + 2 * wave + lane] =
          (lane ? p1 : p0) * (1.0f / sc_lds[0]);
    if (t == MAXLEN) break;

    // ---- dots + early push: all operands in registers / LDS ----
    {
      const float4 hh0 = ((const float4*)h_lds)[lane];
      const float4 hh1 = ((const float4*)h_lds)[lane + 64];
      const float d0 = wred(dot8(k0a, k0b, hh0, hh1));
      const float d1 = wred(dot8(k1a, k1b, hh0, hh1));
      p0 = expf(d0 * SCALE);
      p1 = expf(d1 * SCALE);
      const float fold = p0 * Mr0 + p1 * Mr1;
      if (wave == 0) {
        // wave0: wait for the 15 other partials (intra-CU LDS spin), reduce,
        // and issue the 41 RMW adds BEFORE barrier C -> acks drain inside
        // the barrier, overlapped with waves 1-6's aux dots.
        while (ld_lds_acq(&pwc) < 15 * (t + 1)) __builtin_amdgcn_s_sleep(1);
        float s = fold;
#pragma unroll
        for (int w2 = 1; w2 < NW; ++w2) s += pw_lds[w2 * 48 + lane];
        if (lane < 41)
          atomicAdd(&ws[WS_ACC + (t % 3) * SLOT + g * GSTRIDE + lane], s);
      } else {
        if (lane < 41) pw_lds[wave * 48 + lane] = fold;
        if (lane == 0) inc_lds_rel(&pwc);
        if (wave >= 1 && wave <= 6) {  // gh_t row for step t+1
          const float d = wred(dot8(xa0, xa1, hh0, hh1));
          if (lane == 0)
            st_af(&ws[WS_GH + (t % 3) * 1536 + b * 6 + (wave - 1)], d + xb);
        } else if (wave == 7 && b >= 1 && b <= NV) {  // hp row
          const float d = wred(dot8(xa0, xa1, hh0, hh1));
          if (lane == 0)
            st_af(&ws[WS_ACC + (t % 3) * SLOT + HPOFF + (b - 1)], d + xb);
        } else if (wave == 15 && b < NG) {  // zero slot (t+1)%3 group b
          float* nx = ws + WS_ACC + ((t + 1) % 3) * SLOT + b * GSTRIDE;
          if (lane < 41) st_af(&nx[lane], 0.0f);
          else if (lane == 41) st_ai((int*)&nx[GCNT], 0);
        }
      }
    }
    __syncthreads();  // barrier C: adds/gh/hp/zero all performed at MALL

    // ---- release: the ONLY post-barrier publication op ----
    if (tid == 0)
      __hip_atomic_fetch_add(
          (int*)(ws + WS_ACC + (t % 3) * SLOT + g * GSTRIDE + GCNT), 1,
          __ATOMIC_RELEASE, __HIP_MEMORY_SCOPE_AGENT);
  }
}

extern "C" void kernel_launch(void* const* d_in, const int* in_sizes, int n_in,
                              void* d_out, int out_size, void* d_ws,
                              size_t ws_size, hipStream_t stream) {
  const float* enc    = (const float*)d_in[0];
  const float* hidden = (const float*)d_in[1];
  const float* embed  = (const float*)d_in[2];
  const float* w_ih   = (const float*)d_in[3];
  const float* w_hh   = (const float*)d_in[4];
  const float* b_ih   = (const float*)d_in[5];
  const float* b_hh   = (const float*)d_in[6];
  const float* w_out  = (const float*)d_in[7];
  const float* b_out  = (const float*)d_in[8];
  float* out = (float*)d_out;
  float* ws  = (float*)d_ws;

  dec_init<<<dim3(1), dim3(NT), 0, stream>>>((int*)d_ws);
  dec_main<<<dim3(NB), dim3(NT), 0, stream>>>(enc, hidden, embed, w_ih, w_hh,
                                              b_ih, b_hh, w_out, b_out, out,
                                              ws);
}